// Round 4
// baseline (73.623 us; speedup 1.0000x reference)
//
#include <hip/hip_runtime.h>

#define NB 16
#define NA 76725
#define NC 8
#define NM 32
#define FEPS 1e-4f
#define APT 2                     // anchors per thread
#define TPB 256
#define ANCH_PER_BLK (APT * TPB)  // 512

// ws layout (floats):
//  [WS_ACC .. +64)   per-image acc: {cls_sum, reg_sum, npos(uint), pad} x16
//  [WS_NVP .. +16)   padded valid count per image
//  [WS_CNT .. +16)   num_valid per image
//  [WS_REC .. +NB*NM*8)  per (b,m) record {x1,y1,x2+1,y2+1,area2,lab,pad,pad} (32B)
//  [WS_EPI .. +NB*NM*4)  per (b,m) float4 {gcx,gcy,log(gw),log(gh)}
#define WS_ACC 0
#define WS_NVP 64
#define WS_CNT 80
#define WS_REC 96
#define WS_EPI (WS_REC + NB * NM * 8)   // 4192

__global__ __launch_bounds__(64) void focal_prep(
    const float* __restrict__ ann_, float* __restrict__ ws)
{
    const int b = blockIdx.x;
    const int m = threadIdx.x;
    if (m < 4) ws[WS_ACC + b * 4 + m] = 0.f;   // replaces hipMemsetAsync
    bool valid = false;
    float x1 = 0.f, y1 = 0.f, x2 = 0.f, y2 = 0.f, lab = -1.f;
    if (m < NM) {
        const float* r = ann_ + ((size_t)b * NM + m) * 5;
        x1 = r[0]; y1 = r[1]; x2 = r[2]; y2 = r[3]; lab = r[4];
        valid = lab > -0.5f;
        // sentinel record: inter==0 -> never beats init (ib=0, ub=1)
        float* rec = ws + WS_REC + ((size_t)b * NM + m) * 8;
        rec[0] = 3e18f; rec[1] = 3e18f; rec[2] = -3e18f; rec[3] = -3e18f;
        rec[4] = 1.0f;  rec[5] = -1.f;  rec[6] = 0.f;    rec[7] = 0.f;
        reinterpret_cast<float4*>(ws + WS_EPI)[b * NM + m] = make_float4(0.f, 0.f, 0.f, 0.f);
    }
    const unsigned long long mask = __ballot(valid);
    const int cnt = __popcll(mask);
    __syncthreads();
    if (valid) {
        const int idx = __popcll(mask & ((1ull << m) - 1ull));  // stable compaction
        float* rec = ws + WS_REC + ((size_t)b * NM + idx) * 8;
        rec[0] = x1; rec[1] = y1; rec[2] = x2 + 1.f; rec[3] = y2 + 1.f;
        rec[4] = (x2 - x1 + 1.f) * (y2 - y1 + 1.f);
        rec[5] = lab;
        const float w0 = x2 - x1, h0 = y2 - y1;
        reinterpret_cast<float4*>(ws + WS_EPI)[b * NM + idx] =
            make_float4(x1 + 0.5f * w0, y1 + 0.5f * h0,
                        __logf(fmaxf(w0, 1.f)), __logf(fmaxf(h0, 1.f)));
    }
    if (m == 0) {
        ws[WS_CNT + b] = (float)cnt;
        ws[WS_NVP + b] = (float)((cnt + 7) & ~7);
    }
}

// tab and acc are disjoint regions of d_ws; __restrict__ lets uniform loads
// from tab become s_load (the R2 failure was atomics + loads on ONE pointer).
__global__ __launch_bounds__(TPB) void focal_main(
    const float* __restrict__ cls_,
    const float* __restrict__ reg_,
    const float* __restrict__ anch_,
    const float* __restrict__ tab,
    float* __restrict__ acc)
{
    const int b   = blockIdx.y;
    const int tid = threadIdx.x;

    int nvp = (int)tab[WS_NVP + b];
    nvp = __builtin_amdgcn_readfirstlane(nvp);   // wave-uniform scalar loop bound

    const int a0 = blockIdx.x * ANCH_PER_BLK + tid;

    // ---- issue ALL global loads up front (8x dwordx4 in flight per thread)
    bool   amask[APT];
    float4 an[APT], rg[APT], cv0[APT], cv1[APT];
    #pragma unroll
    for (int k = 0; k < APT; ++k) {
        const int a = a0 + k * TPB;
        amask[k] = (a < NA);
        const int ac = amask[k] ? a : (NA - 1);        // clamp, mask later
        const size_t base = (size_t)b * NA + ac;
        an[k]  = reinterpret_cast<const float4*>(anch_)[base];
        rg[k]  = reinterpret_cast<const float4*>(reg_)[base];
        cv0[k] = reinterpret_cast<const float4*>(cls_)[base * 2];
        cv1[k] = reinterpret_cast<const float4*>(cls_)[base * 2 + 1];
    }

    float ax[APT], ay[APT], az1[APT], aw1[APT], area1[APT];
    float ib[APT], ub[APT];
    int   arg[APT];
    #pragma unroll
    for (int k = 0; k < APT; ++k) {
        ax[k]  = an[k].x; ay[k] = an[k].y;
        az1[k] = an[k].z + 1.f; aw1[k] = an[k].w + 1.f;
        area1[k] = (an[k].z - ax[k] + 1.f) * (an[k].w - ay[k] + 1.f);
        ib[k] = 0.f; ub[k] = 1.f; arg[k] = 0;
    }

    const float* rec = tab + WS_REC + (size_t)b * NM * 8;  // uniform base
    #pragma unroll 4
    for (int m = 0; m < nvp; ++m) {
        const float x1  = rec[m * 8 + 0];   // uniform -> s_load_dwordx8 group
        const float y1  = rec[m * 8 + 1];
        const float x21 = rec[m * 8 + 2];
        const float y21 = rec[m * 8 + 3];
        const float a2  = rec[m * 8 + 4];
        #pragma unroll
        for (int k = 0; k < APT; ++k) {
            const float w = fminf(az1[k], x21) - fmaxf(ax[k], x1);
            const float h = fminf(aw1[k], y21) - fmaxf(ay[k], y1);
            const float inter = fmaxf(w, 0.f) * fmaxf(h, 0.f);
            const float u = area1[k] + a2 - inter;
            const bool better = inter * ub[k] > ib[k] * u;  // strict >: first-occurrence
            ib[k]  = better ? inter : ib[k];
            ub[k]  = better ? u : ub[k];
            arg[k] = better ? m : arg[k];
        }
    }

    float cls_c = 0.f, reg_c = 0.f;
    unsigned pos_c = 0;

    #pragma unroll
    for (int k = 0; k < APT; ++k) {
        const bool pos = ib[k] >= 0.4f * ub[k];
        const bool neg = ib[k] <  0.3f * ub[k];
        const bool act = (pos || neg) && amask[k];

        float pcl[8];
        {
            const float pv[8] = {cv0[k].x, cv0[k].y, cv0[k].z, cv0[k].w,
                                 cv1[k].x, cv1[k].y, cv1[k].z, cv1[k].w};
            float bsum = 0.f;
            #pragma unroll
            for (int c = 0; c < NC; ++c) {
                const float p = fminf(fmaxf(pv[c], FEPS), 1.f - FEPS);
                pcl[c] = p;
                bsum += 0.75f * p * p * (-__logf(1.f - p));   // 8 independent chains
            }
            float contrib = bsum;
            if (pos) {
                const int labi = (int)rec[arg[k] * 8 + 5];    // divergent, L2-hot
                const float t0 = (labi & 1) ? pcl[1] : pcl[0];
                const float t1 = (labi & 1) ? pcl[3] : pcl[2];
                const float t2 = (labi & 1) ? pcl[5] : pcl[4];
                const float t3 = (labi & 1) ? pcl[7] : pcl[6];
                const float u0 = (labi & 2) ? t1 : t0;
                const float u1 = (labi & 2) ? t3 : t2;
                const float pt = (labi & 4) ? u1 : u0;
                const float om = 1.f - pt;
                contrib += 0.25f * om * om * (-__logf(pt))
                         - 0.75f * pt * pt * (-__logf(om));
            }
            cls_c += act ? contrib : 0.f;
        }

        if (pos && amask[k]) {
            pos_c += 1;
            const float4 ep = reinterpret_cast<const float4*>(tab + WS_EPI)[b * NM + arg[k]];
            const float awd = az1[k] - 1.f - ax[k];    // no +1 for regression geometry
            const float ahd = aw1[k] - 1.f - ay[k];
            const float acx = ax[k] + 0.5f * awd;
            const float acy = ay[k] + 0.5f * ahd;
            const float t0 = __fdividef(ep.x - acx, awd) * 10.f;
            const float t1 = __fdividef(ep.y - acy, ahd) * 10.f;
            const float t2 = (ep.z - __logf(awd)) * 5.f;
            const float t3 = (ep.w - __logf(ahd)) * 5.f;
            const float d0 = fabsf(t0 - rg[k].x);
            const float d1 = fabsf(t1 - rg[k].y);
            const float d2 = fabsf(t2 - rg[k].z);
            const float d3 = fabsf(t3 - rg[k].w);
            auto sl1 = [](float d) {
                return d <= (1.f / 9.f) ? 4.5f * d * d : d - (0.5f / 9.f);
            };
            reg_c += sl1(d0) + sl1(d1) + sl1(d2) + sl1(d3);
        }
    }

    // wave-64 shuffle reduction, cross-wave via LDS, 3 atomics per block
    #pragma unroll
    for (int off = 32; off > 0; off >>= 1) {
        cls_c += __shfl_down(cls_c, off);
        reg_c += __shfl_down(reg_c, off);
        pos_c += __shfl_down(pos_c, off);
    }
    __shared__ float    sc[4], sr[4];
    __shared__ unsigned sp[4];
    const int wave = tid >> 6, lane = tid & 63;
    if (lane == 0) { sc[wave] = cls_c; sr[wave] = reg_c; sp[wave] = pos_c; }
    __syncthreads();
    if (tid == 0) {
        const float    c = sc[0] + sc[1] + sc[2] + sc[3];
        const float    r = sr[0] + sr[1] + sr[2] + sr[3];
        const unsigned p = sp[0] + sp[1] + sp[2] + sp[3];
        atomicAdd(&acc[WS_ACC + b * 4 + 0], c);
        atomicAdd(&acc[WS_ACC + b * 4 + 1], r);
        atomicAdd(reinterpret_cast<unsigned*>(acc) + WS_ACC + b * 4 + 2, p);
    }
}

__global__ __launch_bounds__(64) void focal_finalize(
    const float* __restrict__ ws, float* __restrict__ out)
{
    __shared__ float s_cls[NB], s_reg[NB];
    const int b = threadIdx.x;
    if (b < NB) {
        const float    nv      = ws[WS_CNT + b];
        const float    cls_sum = ws[WS_ACC + b * 4 + 0];
        const float    reg_sum = ws[WS_ACC + b * 4 + 1];
        const unsigned npos    = reinterpret_cast<const unsigned*>(ws)[WS_ACC + b * 4 + 2];
        float cl = cls_sum / fmaxf((float)npos, 1.f);
        float rl = (npos > 0u) ? reg_sum / (float)(npos * 4u) : 0.f;
        if (nv < 0.5f) { cl = 0.f; rl = 0.f; }
        s_cls[b] = cl;
        s_reg[b] = rl;
    }
    __syncthreads();
    if (threadIdx.x == 0) {
        float c = 0.f, r = 0.f;
        for (int i = 0; i < NB; ++i) { c += s_cls[i]; r += s_reg[i]; }
        out[0] = c * (1.f / NB);
        out[1] = r * (1.f / NB);
    }
}

extern "C" void kernel_launch(void* const* d_in, const int* in_sizes, int n_in,
                              void* d_out, int out_size, void* d_ws, size_t ws_size,
                              hipStream_t stream)
{
    const float* cls_  = (const float*)d_in[0];
    const float* reg_  = (const float*)d_in[1];
    const float* anch_ = (const float*)d_in[2];
    const float* ann_  = (const float*)d_in[3];
    float* ws  = (float*)d_ws;
    float* out = (float*)d_out;

    focal_prep<<<NB, 64, 0, stream>>>(ann_, ws);
    dim3 grid((NA + ANCH_PER_BLK - 1) / ANCH_PER_BLK, NB);
    focal_main<<<grid, dim3(TPB), 0, stream>>>(cls_, reg_, anch_, ws, ws);
    focal_finalize<<<1, 64, 0, stream>>>(ws, out);
}